// Round 4
// baseline (30.451 us; speedup 1.0000x reference)
//
#include <hip/hip_runtime.h>
#include <hip/hip_bf16.h>

typedef __bf16 bf16x8 __attribute__((ext_vector_type(8)));
typedef float f32x4 __attribute__((ext_vector_type(4)));

#define BATCH 2048
#define NEGS 512
#define IN_DIM 256
#define NGATE 384          // 6 * 64
#define EMB_LD 72          // padded bf16 row stride (144 B = 9*16B: aligned, odd 16B-slot count)
#define TAB_LD 33          // bf16 table row stride

__device__ inline bf16x8 cvt8(float4 f0, float4 f1) {
    bf16x8 r;
    r[0] = (__bf16)f0.x; r[1] = (__bf16)f0.y; r[2] = (__bf16)f0.z; r[3] = (__bf16)f0.w;
    r[4] = (__bf16)f1.x; r[5] = (__bf16)f1.y; r[6] = (__bf16)f1.z; r[7] = (__bf16)f1.w;
    return r;
}

// One fused kernel. Block = 8 consecutive batch rows, 512 threads (8 waves).
// Phase 1: label prefetch + emb->LDS staging + per-block gate GEMM (gates -> LDS).
// Phase 2: two chunks of 4 b's: build 24 bf16 tables via MFMA, then table-lookup scoring.
// emb head rows (sorted): cf_perm=0, cf_primary=1, cf_secondary=2, predictor=3, reorder=4
// label cols: predictor=0, cf_perm=1, cf_primary=2, cf_secondary=3, reorder=4 (5 unused)
// pair p: a-head = predictor(p<3)/reorder(p>=3), c-head = p%3
__global__ __launch_bounds__(512, 2) void fused_pairwise_kernel(
    const float* __restrict__ x, const int* __restrict__ labels,
    const float* __restrict__ emb, const float* __restrict__ gw,
    const float* __restrict__ gb, float* __restrict__ out)
{
    __shared__ __align__(16) __bf16 embs[5 * 32 * EMB_LD];  // 23040 B
    __shared__ __align__(16) __bf16 gls[8 * NGATE];         // 6144 B
    __shared__ __align__(16) __bf16 tab[24 * 32 * TAB_LD];  // 50688 B  (total ~79.9 KB)

    const int t = threadIdx.x;
    const int w = t >> 6, l = t & 63;
    const int lm = l & 15, lq = l >> 4;
    const int b0 = blockIdx.x * 8;

    // ---- label prefetch: chunk c handles b = b0 + 4c + (t>>7), negs 4*(t&127)..+3 ----
    int4 lab[2][6];
#pragma unroll
    for (int c = 0; c < 2; ++c) {
        const int bb = b0 + c * 4 + (t >> 7);
        const int4* lp = (const int4*)(labels + (size_t)bb * NEGS * 6 + (size_t)(t & 127) * 24);
#pragma unroll
        for (int i = 0; i < 6; ++i) lab[c][i] = lp[i];
    }

    // ---- stage emb: f32 global -> bf16 LDS (padded), 1280 8-elem chunks over 512 threads ----
#pragma unroll
    for (int c = 0; c < 3; ++c) {
        const int j = t + c * 512;
        if (j < 1280) {
            const int head = j >> 8, rem = j & 255;
            const int v = rem >> 3, qq = rem & 7;
            const float4* src = (const float4*)(emb + (size_t)j * 8);
            *(bf16x8*)&embs[head * (32 * EMB_LD) + v * EMB_LD + qq * 8] = cvt8(src[0], src[1]);
        }
    }

    // ---- gate GEMM for this block's 8 b's: M=8 (rows 8..15 dup), N=384, K=256 ----
    // wave w computes n-tiles w*3 .. w*3+2; gates -> LDS as bf16
    {
        const float* xp = x + (size_t)(b0 + (lm & 7)) * IN_DIM + lq * 8;
        f32x4 acc[3] = {};
#pragma unroll
        for (int s = 0; s < 8; ++s) {
            const bf16x8 a = cvt8(*(const float4*)(xp + s * 32), *(const float4*)(xp + s * 32 + 4));
#pragma unroll
            for (int j = 0; j < 3; ++j) {
                const int nt = w * 3 + j;
                const float* wp = gw + (size_t)(nt * 16 + lm) * IN_DIM + s * 32 + lq * 8;
                const bf16x8 bv = cvt8(*(const float4*)wp, *(const float4*)(wp + 4));
                acc[j] = __builtin_amdgcn_mfma_f32_16x16x32_bf16(a, bv, acc[j], 0, 0, 0);
            }
        }
        // C/D layout: col = lane&15, row = (lane>>4)*4 + reg ; only rows 0..7 are real b's
#pragma unroll
        for (int j = 0; j < 3; ++j) {
            const int col = (w * 3 + j) * 16 + lm;
            const float bias = gb[col];
#pragma unroll
            for (int r = 0; r < 4; ++r) {
                const int row = lq * 4 + r;
                if (row < 8) gls[row * NGATE + col] = (__bf16)tanhf(acc[j][r] + bias);
            }
        }
    }
    __syncthreads();

    // ---- two chunks of 4 b's each ----
    for (int c = 0; c < 2; ++c) {
        if (c) __syncthreads();   // previous chunk's scoring done before overwriting tables

        // build 24 tables: wave w builds ids w*3 .. w*3+2 ; id = bi*6 + p
#pragma unroll
        for (int j = 0; j < 3; ++j) {
            const int id = w * 3 + j;
            const int bi = id / 6, p = id % 6;
            const int brow = c * 4 + bi;               // b-in-block
            const int arow = (p < 3) ? 3 : 4;          // predictor / reorder
            const int crow = (p < 3) ? p : p - 3;      // cf_perm / cf_primary / cf_secondary
            f32x4 acc[2][2] = {};

#pragma unroll
            for (int s = 0; s < 2; ++s) {
                const int k0 = s * 32 + lq * 8;
                const bf16x8 gsv = *(const bf16x8*)(gls + brow * NGATE + p * 64 + k0);
                float gf[8];
#pragma unroll
                for (int i = 0; i < 8; ++i) gf[i] = (float)gsv[i];

                bf16x8 bfr[2], afr[2];
#pragma unroll
                for (int nh = 0; nh < 2; ++nh)
                    bfr[nh] = *(const bf16x8*)&embs[crow * (32 * EMB_LD) + (nh * 16 + lm) * EMB_LD + k0];
#pragma unroll
                for (int mh = 0; mh < 2; ++mh) {
                    const bf16x8 ea = *(const bf16x8*)&embs[arow * (32 * EMB_LD) + (mh * 16 + lm) * EMB_LD + k0];
                    bf16x8 r;
#pragma unroll
                    for (int i = 0; i < 8; ++i) r[i] = (__bf16)((float)ea[i] * gf[i]);
                    afr[mh] = r;
                }
#pragma unroll
                for (int mh = 0; mh < 2; ++mh)
#pragma unroll
                    for (int nh = 0; nh < 2; ++nh)
                        acc[mh][nh] = __builtin_amdgcn_mfma_f32_16x16x32_bf16(afr[mh], bfr[nh], acc[mh][nh], 0, 0, 0);
            }

            __bf16* tb = tab + id * (32 * TAB_LD);
#pragma unroll
            for (int mh = 0; mh < 2; ++mh)
#pragma unroll
                for (int nh = 0; nh < 2; ++nh) {
                    const int col = nh * 16 + lm;
#pragma unroll
                    for (int r = 0; r < 4; ++r)
                        tb[(mh * 16 + lq * 4 + r) * TAB_LD + col] = (__bf16)acc[mh][nh][r];
                }
        }
        __syncthreads();

        // ---- score 4 negs with this chunk's tables (labels already in regs) ----
        const int bi = t >> 7;
        const __bf16* tb = tab + bi * (6 * 32 * TAB_LD);
        const int4 l0 = lab[c][0], l1 = lab[c][1], l2 = lab[c][2];
        const int4 l3 = lab[c][3], l4 = lab[c][4], l5 = lab[c][5];

        float4 res;
        {   // neg0: cols = l0.xyzw, l1.x
            res.x = (float)tb[0 * 32 * TAB_LD + l0.x * TAB_LD + l0.y] +
                    (float)tb[1 * 32 * TAB_LD + l0.x * TAB_LD + l0.z] +
                    (float)tb[2 * 32 * TAB_LD + l0.x * TAB_LD + l0.w] +
                    (float)tb[3 * 32 * TAB_LD + l1.x * TAB_LD + l0.y] +
                    (float)tb[4 * 32 * TAB_LD + l1.x * TAB_LD + l0.z] +
                    (float)tb[5 * 32 * TAB_LD + l1.x * TAB_LD + l0.w];
        }
        {   // neg1: cols = l1.zw, l2.xy, l2.z
            res.y = (float)tb[0 * 32 * TAB_LD + l1.z * TAB_LD + l1.w] +
                    (float)tb[1 * 32 * TAB_LD + l1.z * TAB_LD + l2.x] +
                    (float)tb[2 * 32 * TAB_LD + l1.z * TAB_LD + l2.y] +
                    (float)tb[3 * 32 * TAB_LD + l2.z * TAB_LD + l1.w] +
                    (float)tb[4 * 32 * TAB_LD + l2.z * TAB_LD + l2.x] +
                    (float)tb[5 * 32 * TAB_LD + l2.z * TAB_LD + l2.y];
        }
        {   // neg2: cols = l3.xyzw, l4.x
            res.z = (float)tb[0 * 32 * TAB_LD + l3.x * TAB_LD + l3.y] +
                    (float)tb[1 * 32 * TAB_LD + l3.x * TAB_LD + l3.z] +
                    (float)tb[2 * 32 * TAB_LD + l3.x * TAB_LD + l3.w] +
                    (float)tb[3 * 32 * TAB_LD + l4.x * TAB_LD + l3.y] +
                    (float)tb[4 * 32 * TAB_LD + l4.x * TAB_LD + l3.z] +
                    (float)tb[5 * 32 * TAB_LD + l4.x * TAB_LD + l3.w];
        }
        {   // neg3: cols = l4.zw, l5.xy, l5.z
            res.w = (float)tb[0 * 32 * TAB_LD + l4.z * TAB_LD + l4.w] +
                    (float)tb[1 * 32 * TAB_LD + l4.z * TAB_LD + l5.x] +
                    (float)tb[2 * 32 * TAB_LD + l4.z * TAB_LD + l5.y] +
                    (float)tb[3 * 32 * TAB_LD + l5.z * TAB_LD + l4.w] +
                    (float)tb[4 * 32 * TAB_LD + l5.z * TAB_LD + l5.x] +
                    (float)tb[5 * 32 * TAB_LD + l5.z * TAB_LD + l5.y];
        }
        const int bb = b0 + c * 4 + bi;
        *(float4*)(out + (size_t)bb * NEGS + (size_t)(t & 127) * 4) = res;
    }
}

extern "C" void kernel_launch(void* const* d_in, const int* in_sizes, int n_in,
                              void* d_out, int out_size, void* d_ws, size_t ws_size,
                              hipStream_t stream) {
    const float* x      = (const float*)d_in[0];
    const int*   labels = (const int*)d_in[1];
    const float* emb    = (const float*)d_in[2];
    const float* gw     = (const float*)d_in[3];
    const float* gb     = (const float*)d_in[4];
    float* out = (float*)d_out;

    hipLaunchKernelGGL(fused_pairwise_kernel, dim3(BATCH / 8), dim3(512), 0, stream,
                       x, labels, emb, gw, gb, out);
}

// Round 5
// 26.466 us; speedup vs baseline: 1.1506x; 1.1506x over previous
//
#include <hip/hip_runtime.h>
#include <hip/hip_bf16.h>

typedef __bf16 bf16x8 __attribute__((ext_vector_type(8)));
typedef float f32x4 __attribute__((ext_vector_type(4)));

#define BATCH 2048
#define NEGS 512
#define IN_DIM 256
#define NGATE 384          // 6 * 64
#define EMB_LD 72          // padded bf16 row stride
#define TAB_LD 34          // bf16 table row stride (68B, dword-aligned)

__device__ inline bf16x8 cvt8(float4 f0, float4 f1) {
    bf16x8 r;
    r[0] = (__bf16)f0.x; r[1] = (__bf16)f0.y; r[2] = (__bf16)f0.z; r[3] = (__bf16)f0.w;
    r[4] = (__bf16)f1.x; r[5] = (__bf16)f1.y; r[6] = (__bf16)f1.z; r[7] = (__bf16)f1.w;
    return r;
}

// tanh(x) = 1 - 2/(e^2x + 1); e^±inf handled (-> ±1), ~6 VALU instr vs ocml's ~40.
__device__ inline float fast_tanh(float v) {
    float e = __expf(2.f * v);
    return 1.f - 2.f * __builtin_amdgcn_rcpf(e + 1.f);
}

// ---------------- Kernel 1: g[b][p*64+d] = tanh(x[b,:] . gate_w[p,d,:] + gate_b[p,d]) -> bf16
// M=2048, N=384, K=256. Each wave: one 16-row m-tile x one 32-col n-pair (A-frag shared
// across 2 MFMAs). 1536 wave-tasks = 384 blocks x 4 waves; unroll 2 keeps VGPR < 128 so
// __launch_bounds__(256,4) holds 16 waves/CU.
__global__ __launch_bounds__(256, 4) void gate_gemm_kernel(
    const float* __restrict__ x, const float* __restrict__ gw,
    const float* __restrict__ gb, __bf16* __restrict__ g)
{
    const int w = threadIdx.x >> 6, l = threadIdx.x & 63;
    const int lm = l & 15, lq = l >> 4;
    const int task = blockIdx.x * 4 + w;      // 0..1535
    const int mt = task / 12, np = task % 12; // block's waves share x rows (L1/L2)
    const int m0 = mt * 16, n0 = np * 32;

    const float* xp  = x  + (size_t)(m0 + lm) * IN_DIM + lq * 8;
    const float* wp0 = gw + (size_t)(n0 + lm) * IN_DIM + lq * 8;
    const float* wp1 = wp0 + 16 * IN_DIM;
    f32x4 acc0 = {}, acc1 = {};
#pragma unroll 2
    for (int s = 0; s < 8; ++s) {
        const bf16x8 a  = cvt8(*(const float4*)(xp  + s * 32), *(const float4*)(xp  + s * 32 + 4));
        const bf16x8 b0 = cvt8(*(const float4*)(wp0 + s * 32), *(const float4*)(wp0 + s * 32 + 4));
        const bf16x8 b1 = cvt8(*(const float4*)(wp1 + s * 32), *(const float4*)(wp1 + s * 32 + 4));
        acc0 = __builtin_amdgcn_mfma_f32_16x16x32_bf16(a, b0, acc0, 0, 0, 0);
        acc1 = __builtin_amdgcn_mfma_f32_16x16x32_bf16(a, b1, acc1, 0, 0, 0);
    }
    // C/D layout: col = lane&15, row = (lane>>4)*4 + reg
    const int col0 = n0 + lm, col1 = col0 + 16;
    const float bias0 = gb[col0], bias1 = gb[col1];
#pragma unroll
    for (int r = 0; r < 4; ++r) {
        const int row = m0 + lq * 4 + r;
        g[(size_t)row * NGATE + col0] = (__bf16)fast_tanh(acc0[r] + bias0);
        g[(size_t)row * NGATE + col1] = (__bf16)fast_tanh(acc1[r] + bias1);
    }
}

// ---------------- Kernel 2: per-b pair tables via MFMA, then table-lookup scoring -------------
// (identical to the 27.1 us best run: 2 b's/block, bf16 tables, 48 KB LDS -> 3 blk/CU)
// emb rows (sorted heads): cf_perm=0, cf_primary=1, cf_secondary=2, predictor=3, reorder=4
// label cols: predictor=0, cf_perm=1, cf_primary=2, cf_secondary=3, reorder=4 (5 unused)
// pairs p: a-head = pred(p<3)/reorder(p>=3), c-head = p%3
__global__ __launch_bounds__(256, 3) void table_score_kernel(
    const int* __restrict__ labels, const float* __restrict__ emb,
    const __bf16* __restrict__ g, float* __restrict__ out)
{
    __shared__ __align__(16) __bf16 embs[5 * 32 * EMB_LD];    // 23040 B
    __shared__ __align__(16) __bf16 tab[2 * 6 * 32 * TAB_LD]; // 26112 B

    const int t = threadIdx.x;
    const int b0 = blockIdx.x * 2;
    const int w = t >> 6, l = t & 63;
    const int lm = l & 15, lq = l >> 4;

    // ---- prefetch labels (HBM, ~900cy) and gate fragments early ----
    int4 q[2][3];
#pragma unroll
    for (int bi = 0; bi < 2; ++bi) {
        const int4* lp = (const int4*)(labels + (size_t)(b0 + bi) * NEGS * 6) + 3 * t;
        q[bi][0] = lp[0]; q[bi][1] = lp[1]; q[bi][2] = lp[2];
    }
    bf16x8 gv[3][2];
#pragma unroll
    for (int j = 0; j < 3; ++j) {
        const int id = w + j * 4;            // table id this wave builds
        const int bi = id / 6, p = id % 6;
        const __bf16* gp = g + (size_t)(b0 + bi) * NGATE + p * 64 + lq * 8;
        gv[j][0] = *(const bf16x8*)gp;
        gv[j][1] = *(const bf16x8*)(gp + 32);
    }

    // ---- stage emb: f32 global -> bf16 LDS (padded) ----
#pragma unroll
    for (int c = 0; c < 5; ++c) {
        const int j = t + c * 256;           // 1280 chunks of 8 elems
        const int head = j >> 8;
        const int rem = j & 255;
        const int v = rem >> 3, qq = rem & 7;
        const float4* src = (const float4*)(emb + (size_t)j * 8);
        bf16x8 val = cvt8(src[0], src[1]);
        *(bf16x8*)&embs[head * (32 * EMB_LD) + v * EMB_LD + qq * 8] = val;
    }
    __syncthreads();

    // ---- build 12 tables (2 b's x 6 pairs), 3 per wave ----
#pragma unroll
    for (int j = 0; j < 3; ++j) {
        const int id = w + j * 4;
        const int p = id % 6;
        const int arow = (p < 3) ? 3 : 4;     // predictor / reorder
        const int crow = (p < 3) ? p : p - 3; // cf_perm / cf_primary / cf_secondary
        f32x4 acc[2][2] = {};

#pragma unroll
        for (int s = 0; s < 2; ++s) {
            const int k0 = s * 32 + lq * 8;
            float gf[8];
#pragma unroll
            for (int i = 0; i < 8; ++i) gf[i] = (float)gv[j][s][i];

            bf16x8 bfr[2], afr[2];
#pragma unroll
            for (int nh = 0; nh < 2; ++nh)
                bfr[nh] = *(const bf16x8*)&embs[crow * (32 * EMB_LD) + (nh * 16 + lm) * EMB_LD + k0];
#pragma unroll
            for (int mh = 0; mh < 2; ++mh) {
                bf16x8 ea = *(const bf16x8*)&embs[arow * (32 * EMB_LD) + (mh * 16 + lm) * EMB_LD + k0];
                bf16x8 r;
#pragma unroll
                for (int i = 0; i < 8; ++i) r[i] = (__bf16)((float)ea[i] * gf[i]);
                afr[mh] = r;
            }
#pragma unroll
            for (int mh = 0; mh < 2; ++mh)
#pragma unroll
                for (int nh = 0; nh < 2; ++nh)
                    acc[mh][nh] = __builtin_amdgcn_mfma_f32_16x16x32_bf16(afr[mh], bfr[nh], acc[mh][nh], 0, 0, 0);
        }

        __bf16* tb = tab + id * (32 * TAB_LD);
#pragma unroll
        for (int mh = 0; mh < 2; ++mh)
#pragma unroll
            for (int nh = 0; nh < 2; ++nh) {
                const int col = nh * 16 + lm;
#pragma unroll
                for (int r = 0; r < 4; ++r)
                    tb[(mh * 16 + lq * 4 + r) * TAB_LD + col] = (__bf16)acc[mh][nh][r];
            }
    }
    __syncthreads();

    // ---- score: thread t handles negs {2t, 2t+1} for each of the 2 b's ----
#pragma unroll
    for (int bi = 0; bi < 2; ++bi) {
        const int b = b0 + bi;
        const int4 q0 = q[bi][0];  // negA: cols 0..3
        const int4 q1 = q[bi][1];  // negA: col4, col5 | negB: col0, col1
        const int4 q2 = q[bi][2];  // negB: cols 2..5
        const __bf16* tb = tab + bi * (6 * 32 * TAB_LD);

        const float sA =
            (float)tb[0 * 32 * TAB_LD + q0.x * TAB_LD + q0.y] +
            (float)tb[1 * 32 * TAB_LD + q0.x * TAB_LD + q0.z] +
            (float)tb[2 * 32 * TAB_LD + q0.x * TAB_LD + q0.w] +
            (float)tb[3 * 32 * TAB_LD + q1.x * TAB_LD + q0.y] +
            (float)tb[4 * 32 * TAB_LD + q1.x * TAB_LD + q0.z] +
            (float)tb[5 * 32 * TAB_LD + q1.x * TAB_LD + q0.w];
        const float sB =
            (float)tb[0 * 32 * TAB_LD + q1.z * TAB_LD + q1.w] +
            (float)tb[1 * 32 * TAB_LD + q1.z * TAB_LD + q2.x] +
            (float)tb[2 * 32 * TAB_LD + q1.z * TAB_LD + q2.y] +
            (float)tb[3 * 32 * TAB_LD + q2.z * TAB_LD + q1.w] +
            (float)tb[4 * 32 * TAB_LD + q2.z * TAB_LD + q2.x] +
            (float)tb[5 * 32 * TAB_LD + q2.z * TAB_LD + q2.y];

        float2 res; res.x = sA; res.y = sB;
        *(float2*)(out + (size_t)b * NEGS + 2 * t) = res;
    }
}

extern "C" void kernel_launch(void* const* d_in, const int* in_sizes, int n_in,
                              void* d_out, int out_size, void* d_ws, size_t ws_size,
                              hipStream_t stream) {
    const float* x      = (const float*)d_in[0];
    const int*   labels = (const int*)d_in[1];
    const float* emb    = (const float*)d_in[2];
    const float* gw     = (const float*)d_in[3];
    const float* gb     = (const float*)d_in[4];
    float* out = (float*)d_out;
    __bf16* g  = (__bf16*)d_ws;   // 2048*384 bf16 = 1.5 MB

    hipLaunchKernelGGL(gate_gemm_kernel, dim3(384), dim3(256), 0, stream, x, gw, gb, g);
    hipLaunchKernelGGL(table_score_kernel, dim3(BATCH / 2), dim3(256), 0, stream,
                       labels, emb, g, out);
}

// Round 6
// 26.232 us; speedup vs baseline: 1.1609x; 1.0090x over previous
//
#include <hip/hip_runtime.h>
#include <hip/hip_bf16.h>

typedef __bf16 bf16x8 __attribute__((ext_vector_type(8)));
typedef float f32x4 __attribute__((ext_vector_type(4)));

#define BATCH 2048
#define NEGS 512
#define IN_DIM 256
#define NGATE 384          // 6 * 64
#define EMB_LD 72          // padded bf16 row stride
#define TAB_LD 34          // bf16 table row stride (68B, dword-aligned)
#define EMB_CHUNKS 1536    // 24576 B / 16 B: padded emb image (5*32*72*2 = 23040 B used)

__device__ inline bf16x8 cvt8(float4 f0, float4 f1) {
    bf16x8 r;
    r[0] = (__bf16)f0.x; r[1] = (__bf16)f0.y; r[2] = (__bf16)f0.z; r[3] = (__bf16)f0.w;
    r[4] = (__bf16)f1.x; r[5] = (__bf16)f1.y; r[6] = (__bf16)f1.z; r[7] = (__bf16)f1.w;
    return r;
}

// tanh(x) = 1 - 2/(e^2x + 1); ~6 VALU instr vs ocml's ~40.
__device__ inline float fast_tanh(float v) {
    float e = __expf(2.f * v);
    return 1.f - 2.f * __builtin_amdgcn_rcpf(e + 1.f);
}

// ---------------- Kernel 1: gate GEMM (-> bf16 g) + emb pre-conversion block ------------------
// Blocks 0..383: M=2048, N=384, K=256; one 16-row m-tile x 32-col n-pair per wave.
// Block 384: convert emb f32 -> bf16 in the EXACT padded byte-layout K2's LDS uses
//            (zero-filled pads for deterministic bytes).
__global__ __launch_bounds__(256, 4) void gate_gemm_kernel(
    const float* __restrict__ x, const float* __restrict__ gw,
    const float* __restrict__ gb, const float* __restrict__ emb,
    __bf16* __restrict__ g, __bf16* __restrict__ embws)
{
    const int t = threadIdx.x;
    if (blockIdx.x == 384) {
        // zero-fill the padded image, then overwrite the live lanes
        bf16x8 z = {};
#pragma unroll
        for (int r = 0; r < 6; ++r)
            *(bf16x8*)&embws[(size_t)(r * 256 + t) * 8] = z;
        __syncthreads();
#pragma unroll
        for (int c = 0; c < 5; ++c) {
            const int j = t + c * 256;            // 1280 chunks of 8 f32
            const int head = j >> 8, rem = j & 255;
            const int v = rem >> 3, qq = rem & 7;
            const float4* src = (const float4*)(emb + (size_t)j * 8);
            *(bf16x8*)&embws[head * (32 * EMB_LD) + v * EMB_LD + qq * 8] = cvt8(src[0], src[1]);
        }
        return;
    }

    const int w = t >> 6, l = t & 63;
    const int lm = l & 15, lq = l >> 4;
    const int task = blockIdx.x * 4 + w;      // 0..1535
    const int mt = task / 12, np = task % 12; // block's waves share x rows (L1/L2)
    const int m0 = mt * 16, n0 = np * 32;

    const float* xp  = x  + (size_t)(m0 + lm) * IN_DIM + lq * 8;
    const float* wp0 = gw + (size_t)(n0 + lm) * IN_DIM + lq * 8;
    const float* wp1 = wp0 + 16 * IN_DIM;
    f32x4 acc0 = {}, acc1 = {};
#pragma unroll 2
    for (int s = 0; s < 8; ++s) {
        const bf16x8 a  = cvt8(*(const float4*)(xp  + s * 32), *(const float4*)(xp  + s * 32 + 4));
        const bf16x8 b0 = cvt8(*(const float4*)(wp0 + s * 32), *(const float4*)(wp0 + s * 32 + 4));
        const bf16x8 b1 = cvt8(*(const float4*)(wp1 + s * 32), *(const float4*)(wp1 + s * 32 + 4));
        acc0 = __builtin_amdgcn_mfma_f32_16x16x32_bf16(a, b0, acc0, 0, 0, 0);
        acc1 = __builtin_amdgcn_mfma_f32_16x16x32_bf16(a, b1, acc1, 0, 0, 0);
    }
    // C/D layout: col = lane&15, row = (lane>>4)*4 + reg
    const int col0 = n0 + lm, col1 = col0 + 16;
    const float bias0 = gb[col0], bias1 = gb[col1];
#pragma unroll
    for (int r = 0; r < 4; ++r) {
        const int row = m0 + lq * 4 + r;
        g[(size_t)row * NGATE + col0] = (__bf16)fast_tanh(acc0[r] + bias0);
        g[(size_t)row * NGATE + col1] = (__bf16)fast_tanh(acc1[r] + bias1);
    }
}

// ---------------- Kernel 2: per-b pair tables via MFMA, then table-lookup scoring -------------
// 2 b's/block, bf16 tables; emb staged by PURE 16B copies from the pre-converted padded image.
// LDS = 24576 (emb) + 26112 (tables) = 50688 B -> 3 blocks/CU.
// emb rows (sorted heads): cf_perm=0, cf_primary=1, cf_secondary=2, predictor=3, reorder=4
// label cols: predictor=0, cf_perm=1, cf_primary=2, cf_secondary=3, reorder=4 (5 unused)
// pairs p: a-head = pred(p<3)/reorder(p>=3), c-head = p%3
__global__ __launch_bounds__(256, 3) void table_score_kernel(
    const int* __restrict__ labels, const __bf16* __restrict__ embws,
    const __bf16* __restrict__ g, float* __restrict__ out)
{
    __shared__ __align__(16) __bf16 embs[EMB_CHUNKS * 8];     // 24576 B, byte-identical to embws
    __shared__ __align__(16) __bf16 tab[2 * 6 * 32 * TAB_LD]; // 26112 B

    const int t = threadIdx.x;
    const int b0 = blockIdx.x * 2;
    const int w = t >> 6, l = t & 63;
    const int lm = l & 15, lq = l >> 4;

    // ---- prefetch labels (HBM, ~900cy) and gate fragments early ----
    int4 q[2][3];
#pragma unroll
    for (int bi = 0; bi < 2; ++bi) {
        const int4* lp = (const int4*)(labels + (size_t)(b0 + bi) * NEGS * 6) + 3 * t;
        q[bi][0] = lp[0]; q[bi][1] = lp[1]; q[bi][2] = lp[2];
    }
    bf16x8 gv[3][2];
#pragma unroll
    for (int j = 0; j < 3; ++j) {
        const int id = w + j * 4;            // table id this wave builds
        const int bi = id / 6, p = id % 6;
        const __bf16* gp = g + (size_t)(b0 + bi) * NGATE + p * 64 + lq * 8;
        gv[j][0] = *(const bf16x8*)gp;
        gv[j][1] = *(const bf16x8*)(gp + 32);
    }

    // ---- stage emb: 6 pure 16B copies per thread (no conversion, half the bytes) ----
#pragma unroll
    for (int r = 0; r < 6; ++r) {
        const int idx = r * 256 + t;         // 1536 chunks
        *(bf16x8*)&embs[(size_t)idx * 8] = *(const bf16x8*)&embws[(size_t)idx * 8];
    }
    __syncthreads();

    // ---- build 12 tables (2 b's x 6 pairs), 3 per wave ----
#pragma unroll
    for (int j = 0; j < 3; ++j) {
        const int id = w + j * 4;
        const int p = id % 6;
        const int arow = (p < 3) ? 3 : 4;     // predictor / reorder
        const int crow = (p < 3) ? p : p - 3; // cf_perm / cf_primary / cf_secondary
        f32x4 acc[2][2] = {};

#pragma unroll
        for (int s = 0; s < 2; ++s) {
            const int k0 = s * 32 + lq * 8;
            float gf[8];
#pragma unroll
            for (int i = 0; i < 8; ++i) gf[i] = (float)gv[j][s][i];

            bf16x8 bfr[2], afr[2];
#pragma unroll
            for (int nh = 0; nh < 2; ++nh)
                bfr[nh] = *(const bf16x8*)&embs[crow * (32 * EMB_LD) + (nh * 16 + lm) * EMB_LD + k0];
#pragma unroll
            for (int mh = 0; mh < 2; ++mh) {
                bf16x8 ea = *(const bf16x8*)&embs[arow * (32 * EMB_LD) + (mh * 16 + lm) * EMB_LD + k0];
                bf16x8 r;
#pragma unroll
                for (int i = 0; i < 8; ++i) r[i] = (__bf16)((float)ea[i] * gf[i]);
                afr[mh] = r;
            }
#pragma unroll
            for (int mh = 0; mh < 2; ++mh)
#pragma unroll
                for (int nh = 0; nh < 2; ++nh)
                    acc[mh][nh] = __builtin_amdgcn_mfma_f32_16x16x32_bf16(afr[mh], bfr[nh], acc[mh][nh], 0, 0, 0);
        }

        __bf16* tb = tab + id * (32 * TAB_LD);
#pragma unroll
        for (int mh = 0; mh < 2; ++mh)
#pragma unroll
            for (int nh = 0; nh < 2; ++nh) {
                const int col = nh * 16 + lm;
#pragma unroll
                for (int r = 0; r < 4; ++r)
                    tb[(mh * 16 + lq * 4 + r) * TAB_LD + col] = (__bf16)acc[mh][nh][r];
            }
    }
    __syncthreads();

    // ---- score: thread t handles negs {2t, 2t+1} for each of the 2 b's ----
#pragma unroll
    for (int bi = 0; bi < 2; ++bi) {
        const int b = b0 + bi;
        const int4 q0 = q[bi][0];  // negA: cols 0..3
        const int4 q1 = q[bi][1];  // negA: col4, col5 | negB: col0, col1
        const int4 q2 = q[bi][2];  // negB: cols 2..5
        const __bf16* tb = tab + bi * (6 * 32 * TAB_LD);

        const float sA =
            (float)tb[0 * 32 * TAB_LD + q0.x * TAB_LD + q0.y] +
            (float)tb[1 * 32 * TAB_LD + q0.x * TAB_LD + q0.z] +
            (float)tb[2 * 32 * TAB_LD + q0.x * TAB_LD + q0.w] +
            (float)tb[3 * 32 * TAB_LD + q1.x * TAB_LD + q0.y] +
            (float)tb[4 * 32 * TAB_LD + q1.x * TAB_LD + q0.z] +
            (float)tb[5 * 32 * TAB_LD + q1.x * TAB_LD + q0.w];
        const float sB =
            (float)tb[0 * 32 * TAB_LD + q1.z * TAB_LD + q1.w] +
            (float)tb[1 * 32 * TAB_LD + q1.z * TAB_LD + q2.x] +
            (float)tb[2 * 32 * TAB_LD + q1.z * TAB_LD + q2.y] +
            (float)tb[3 * 32 * TAB_LD + q2.z * TAB_LD + q1.w] +
            (float)tb[4 * 32 * TAB_LD + q2.z * TAB_LD + q2.x] +
            (float)tb[5 * 32 * TAB_LD + q2.z * TAB_LD + q2.y];

        float2 res; res.x = sA; res.y = sB;
        *(float2*)(out + (size_t)b * NEGS + 2 * t) = res;
    }
}

extern "C" void kernel_launch(void* const* d_in, const int* in_sizes, int n_in,
                              void* d_out, int out_size, void* d_ws, size_t ws_size,
                              hipStream_t stream) {
    const float* x      = (const float*)d_in[0];
    const int*   labels = (const int*)d_in[1];
    const float* emb    = (const float*)d_in[2];
    const float* gw     = (const float*)d_in[3];
    const float* gb     = (const float*)d_in[4];
    float* out = (float*)d_out;
    __bf16* g     = (__bf16*)d_ws;                                  // 1.5 MB
    __bf16* embws = (__bf16*)((char*)d_ws + (size_t)BATCH * NGATE * 2); // 24576 B

    hipLaunchKernelGGL(gate_gemm_kernel, dim3(385), dim3(256), 0, stream,
                       x, gw, gb, emb, g, embws);
    hipLaunchKernelGGL(table_score_kernel, dim3(BATCH / 2), dim3(256), 0, stream,
                       labels, embws, g, out);
}